// Round 1
// baseline (93.778 us; speedup 1.0000x reference)
//
#include <hip/hip_runtime.h>
#include <math.h>

#define BB 32
#define NN 2048
#define DD 2048

// ---------------------------------------------------------------------------
// Kernel 1: scores[b,n] = clip( mask[b,n] * dot(q1[b],k1[b,n]) /
//                               (max(||q1[b]||,1e-12)*max(||k1[b,n]||,1e-12)),
//                               0, 1 )
// grid = B * N/4 blocks, 256 threads = 4 waves, one wave per (b,n) row.
// ---------------------------------------------------------------------------
__global__ __launch_bounds__(256) void score_kernel(
    const float* __restrict__ q1,
    const float* __restrict__ k1,
    const float* __restrict__ mask,
    float* __restrict__ scores)
{
    __shared__ float q_lds[DD];

    const int block  = blockIdx.x;
    const int b      = block >> 9;            // N/4 = 512 blocks per batch
    const int n_base = (block & 511) << 2;    // 4 rows per block
    const int tid    = threadIdx.x;

    // Cooperative load of q1 row into LDS (2048 floats = 512 float4).
    const float4* q4  = (const float4*)(q1 + (size_t)b * DD);
    float4*       ql4 = (float4*)q_lds;
    ql4[tid]       = q4[tid];
    ql4[tid + 256] = q4[tid + 256];
    __syncthreads();

    const int wave = tid >> 6;
    const int lane = tid & 63;
    const int n    = n_base + wave;

    const float4* krow = (const float4*)(k1 + ((size_t)b * NN + n) * (size_t)DD);

    float dot = 0.0f, ksq = 0.0f, qsq = 0.0f;
#pragma unroll
    for (int it = 0; it < 8; ++it) {
        float4 kv = krow[it * 64 + lane];
        float4 qv = ql4 [it * 64 + lane];
        dot = fmaf(qv.x, kv.x, dot);
        dot = fmaf(qv.y, kv.y, dot);
        dot = fmaf(qv.z, kv.z, dot);
        dot = fmaf(qv.w, kv.w, dot);
        ksq = fmaf(kv.x, kv.x, ksq);
        ksq = fmaf(kv.y, kv.y, ksq);
        ksq = fmaf(kv.z, kv.z, ksq);
        ksq = fmaf(kv.w, kv.w, ksq);
        qsq = fmaf(qv.x, qv.x, qsq);
        qsq = fmaf(qv.y, qv.y, qsq);
        qsq = fmaf(qv.z, qv.z, qsq);
        qsq = fmaf(qv.w, qv.w, qsq);
    }

    // wave-wide butterfly reduction (64 lanes)
#pragma unroll
    for (int off = 1; off < 64; off <<= 1) {
        dot += __shfl_xor(dot, off);
        ksq += __shfl_xor(ksq, off);
        qsq += __shfl_xor(qsq, off);
    }

    if (lane == 0) {
        float nq = sqrtf(qsq);
        float nk = sqrtf(ksq);
        float s  = dot / (fmaxf(nq, 1e-12f) * fmaxf(nk, 1e-12f));
        s *= mask[b * NN + n];
        s  = fminf(fmaxf(s, 0.0f), 1.0f);
        scores[b * NN + n] = s;
    }
}

// ---------------------------------------------------------------------------
// Kernel 2: in-place row softmax over N=2048. One block (256 thr) per batch.
// ---------------------------------------------------------------------------
__global__ __launch_bounds__(256) void softmax_kernel(float* __restrict__ inout)
{
    const int b   = blockIdx.x;
    const int tid = threadIdx.x;
    const int wave = tid >> 6;
    const int lane = tid & 63;
    float* row = inout + (size_t)b * NN;

    __shared__ float red_max[4];
    __shared__ float red_sum[4];

    float v[8];
    float m = -INFINITY;
#pragma unroll
    for (int i = 0; i < 8; ++i) {
        v[i] = row[tid + i * 256];
        m = fmaxf(m, v[i]);
    }
#pragma unroll
    for (int off = 1; off < 64; off <<= 1)
        m = fmaxf(m, __shfl_xor(m, off));
    if (lane == 0) red_max[wave] = m;
    __syncthreads();
    m = fmaxf(fmaxf(red_max[0], red_max[1]), fmaxf(red_max[2], red_max[3]));

    float s = 0.0f;
#pragma unroll
    for (int i = 0; i < 8; ++i) {
        v[i] = expf(v[i] - m);
        s += v[i];
    }
#pragma unroll
    for (int off = 1; off < 64; off <<= 1)
        s += __shfl_xor(s, off);
    if (lane == 0) red_sum[wave] = s;
    __syncthreads();
    s = (red_sum[0] + red_sum[1]) + (red_sum[2] + red_sum[3]);

    float inv = 1.0f / s;
#pragma unroll
    for (int i = 0; i < 8; ++i)
        row[tid + i * 256] = v[i] * inv;
}

extern "C" void kernel_launch(void* const* d_in, const int* in_sizes, int n_in,
                              void* d_out, int out_size, void* d_ws, size_t ws_size,
                              hipStream_t stream) {
    const float* q1   = (const float*)d_in[0];
    const float* k1   = (const float*)d_in[1];
    // d_in[2] = q2, d_in[3] = k2, d_in[5] = temp : unused by the reference math
    const float* mask = (const float*)d_in[4];
    float* out = (float*)d_out;

    dim3 grid_score(BB * (NN / 4));
    score_kernel<<<grid_score, 256, 0, stream>>>(q1, k1, mask, out);
    softmax_kernel<<<BB, 256, 0, stream>>>(out);
}

// Round 2
// 83.816 us; speedup vs baseline: 1.1189x; 1.1189x over previous
//
#include <hip/hip_runtime.h>
#include <math.h>

#define BB 32
#define NN 2048
#define DD 2048

typedef float f4v __attribute__((ext_vector_type(4)));

// ---------------------------------------------------------------------------
// Kernel 1: e[b,n] = exp( clip( mask[b,n] * dot(q1[b],k1[b,n]) /
//                         (max(||q1||,1e-12)*max(||k1[b,n]||,1e-12)), 0, 1) )
// written to out; per-block partial sum (4 rows) -> ws[block] (fixed order).
// grid = B * N/4 blocks, 256 threads = 4 waves, one wave per (b,n) row.
// ---------------------------------------------------------------------------
__global__ __launch_bounds__(256) void score_kernel(
    const float* __restrict__ q1,
    const float* __restrict__ k1,
    const float* __restrict__ mask,
    float* __restrict__ out,
    float* __restrict__ partial)
{
    __shared__ f4v  q_lds[DD / 4];
    __shared__ float sm[4];

    const int block  = blockIdx.x;
    const int b      = block >> 9;            // N/4 = 512 blocks per batch
    const int n_base = (block & 511) << 2;    // 4 rows per block
    const int tid    = threadIdx.x;

    // Cooperative load of q1 row into LDS (2048 floats = 512 float4).
    const f4v* q4 = (const f4v*)(q1 + (size_t)b * DD);
    q_lds[tid]       = q4[tid];
    q_lds[tid + 256] = q4[tid + 256];
    __syncthreads();

    const int wave = tid >> 6;
    const int lane = tid & 63;
    const int n    = n_base + wave;

    const f4v* krow = (const f4v*)(k1 + ((size_t)b * NN + n) * (size_t)DD);

    float dot = 0.0f, ksq = 0.0f, qsq = 0.0f;
#pragma unroll
    for (int it = 0; it < 8; ++it) {
        f4v kv = __builtin_nontemporal_load(krow + it * 64 + lane); // streamed once
        f4v qv = q_lds[it * 64 + lane];
        dot = fmaf(qv.x, kv.x, dot);
        dot = fmaf(qv.y, kv.y, dot);
        dot = fmaf(qv.z, kv.z, dot);
        dot = fmaf(qv.w, kv.w, dot);
        ksq = fmaf(kv.x, kv.x, ksq);
        ksq = fmaf(kv.y, kv.y, ksq);
        ksq = fmaf(kv.z, kv.z, ksq);
        ksq = fmaf(kv.w, kv.w, ksq);
        qsq = fmaf(qv.x, qv.x, qsq);
        qsq = fmaf(qv.y, qv.y, qsq);
        qsq = fmaf(qv.z, qv.z, qsq);
        qsq = fmaf(qv.w, qv.w, qsq);
    }

    // wave-wide butterfly reduction (64 lanes)
#pragma unroll
    for (int off = 1; off < 64; off <<= 1) {
        dot += __shfl_xor(dot, off);
        ksq += __shfl_xor(ksq, off);
        qsq += __shfl_xor(qsq, off);
    }

    if (lane == 0) {
        float nq = sqrtf(qsq);
        float nk = sqrtf(ksq);
        float s  = dot / (fmaxf(nq, 1e-12f) * fmaxf(nk, 1e-12f));
        s *= mask[b * NN + n];
        s  = fminf(fmaxf(s, 0.0f), 1.0f);
        float e = expf(s);            // s in [0,1] -> exp in [1,e]: stable, no max needed
        out[b * NN + n] = e;
        sm[wave] = e;
    }
    __syncthreads();
    if (tid == 0)
        partial[block] = (sm[0] + sm[1]) + (sm[2] + sm[3]);  // fixed order
}

// ---------------------------------------------------------------------------
// Kernel 2: out[b,n] *= 1/sum_b.  grid = 256 blocks (8 per batch), 256 thr.
// Every block of a batch reduces the 512 partials in IDENTICAL order ->
// bitwise-identical inverse across segments. Deterministic.
// ---------------------------------------------------------------------------
__global__ __launch_bounds__(256) void scale_kernel(
    float* __restrict__ out,
    const float* __restrict__ partial)
{
    const int blk  = blockIdx.x;
    const int b    = blk >> 3;
    const int seg  = blk & 7;
    const int tid  = threadIdx.x;
    const int wave = tid >> 6;
    const int lane = tid & 63;

    __shared__ float red[4];

    const float* p = partial + b * 512;
    float s = p[tid] + p[tid + 256];
#pragma unroll
    for (int off = 1; off < 64; off <<= 1)
        s += __shfl_xor(s, off);
    if (lane == 0) red[wave] = s;
    __syncthreads();
    float total = (red[0] + red[1]) + (red[2] + red[3]);

    float inv = 1.0f / total;
    const int n = seg * 256 + tid;
    out[(size_t)b * NN + n] *= inv;
}

extern "C" void kernel_launch(void* const* d_in, const int* in_sizes, int n_in,
                              void* d_out, int out_size, void* d_ws, size_t ws_size,
                              hipStream_t stream) {
    const float* q1   = (const float*)d_in[0];
    const float* k1   = (const float*)d_in[1];
    // d_in[2] = q2, d_in[3] = k2, d_in[5] = temp : unused by the reference math
    const float* mask = (const float*)d_in[4];
    float* out     = (float*)d_out;
    float* partial = (float*)d_ws;   // 16384 floats = 64 KB, rewritten every call

    dim3 grid_score(BB * (NN / 4));
    score_kernel<<<grid_score, 256, 0, stream>>>(q1, k1, mask, out, partial);
    scale_kernel<<<BB * 8, 256, 0, stream>>>(out, partial);
}